// Round 3
// baseline (529.409 us; speedup 1.0000x reference)
//
#include <hip/hip_runtime.h>

// DotProcessorBlock: feat = x*w + b (B=4096, N=256); out[b, :] = first
// n(n+1)/2 = 32896 row-major entries of feat ⊗ feat.
// Pure HBM-write-bound: 539 MB out vs 4 MB in.
//
// R3: wave-autonomous version. N=256 fits in 64 lanes x float4 registers,
// so each wave owns one batch independently:
//   - no __shared__, no __syncthreads, no ds_read on the store path
//     (feat[i] broadcast via v_readlane with compile-time lane index -> SGPR)
//   - 1024 blocks x 4 waves = 4096 independent store streams, all
//     resident in one generation (16 waves/CU)
//   - NT stores kept (write-once 539 MB stream; proven neutral, not harmful)
// Theory: old kernel's per-iteration LDS-latency chain + block barrier
// coupling throttled store issue to ~2.9 TB/s vs the 6.3 TB/s the harness
// fill reaches with pure independent wave store streams.

#define NFEAT 256
#define NOUT  32896   // 256*257/2

typedef float f32x4 __attribute__((ext_vector_type(4)));

__device__ __forceinline__ float readlane_f(float v, int lane) {
    return __builtin_bit_cast(float,
        __builtin_amdgcn_readlane(__builtin_bit_cast(int, v), lane));
}

__global__ __launch_bounds__(256) void dot_outer_kernel(
    const float* __restrict__ x,
    const float* __restrict__ w,
    const float* __restrict__ bias,
    float* __restrict__ out)
{
    const int t    = threadIdx.x;
    const int lane = t & 63;
    const int wid  = t >> 6;
    const int b    = (blockIdx.x << 2) + wid;   // one batch per wave

    // Lane L holds feat[4L .. 4L+3] in registers.
    const f32x4 xv = *(const f32x4*)(x    + (size_t)b * NFEAT + 4 * lane);
    const f32x4 wv = *(const f32x4*)(w    + 4 * lane);
    const f32x4 bv = *(const f32x4*)(bias + 4 * lane);

    f32x4 f;
    f.x = xv.x * wv.x + bv.x;
    f.y = xv.y * wv.y + bv.y;
    f.z = xv.z * wv.z + bv.z;
    f.w = xv.w * wv.w + bv.w;

    // Wave writes 1 KB (one dwordx4 per lane) per row.
    f32x4* outw = (f32x4*)(out + (size_t)b * NOUT) + lane;

    // Rows 0..127: feat[i] = component (i&3) of lane (i>>2), broadcast
    // via v_readlane (compile-time constants after full unroll).
    #pragma unroll
    for (int i = 0; i < 128; ++i) {
        float comp;
        switch (i & 3) {
            case 0:  comp = f.x; break;
            case 1:  comp = f.y; break;
            case 2:  comp = f.z; break;
            default: comp = f.w; break;
        }
        const float fi = readlane_f(comp, i >> 2);
        f32x4 v;
        v.x = fi * f.x;
        v.y = fi * f.y;
        v.z = fi * f.z;
        v.w = fi * f.w;
        __builtin_nontemporal_store(v, outw + (size_t)i * 64);
    }

    // Tail: row 128, cols 0..127 -> lanes 0..31 store one float4 each.
    const float fi = readlane_f(f.x, 32);   // feat[128]; readlane ignores exec
    if (lane < 32) {
        f32x4 v;
        v.x = fi * f.x;
        v.y = fi * f.y;
        v.z = fi * f.z;
        v.w = fi * f.w;
        __builtin_nontemporal_store(v, outw + 128 * 64);
    }
}

extern "C" void kernel_launch(void* const* d_in, const int* in_sizes, int n_in,
                              void* d_out, int out_size, void* d_ws, size_t ws_size,
                              hipStream_t stream) {
    const float* x    = (const float*)d_in[0];
    const float* w    = (const float*)d_in[1];
    const float* bias = (const float*)d_in[2];
    float* out = (float*)d_out;

    const int B = in_sizes[0] / NFEAT;     // 4096
    dot_outer_kernel<<<B / 4, 256, 0, stream>>>(x, w, bias, out);
}